// Round 1
// baseline (215.334 us; speedup 1.0000x reference)
//
#include <hip/hip_runtime.h>

typedef __bf16 bf16x8 __attribute__((ext_vector_type(8)));
typedef __bf16 bf16x4 __attribute__((ext_vector_type(4)));
typedef float f32x4 __attribute__((ext_vector_type(4)));
typedef float f32x16 __attribute__((ext_vector_type(16)));

namespace {
constexpr int Bn = 2, Cn = 64, hn = 96, wn = 96, Hn = 384, Wn = 384;
constexpr int CIN = 266;
constexpr int TM = 64;                      // pixels per workgroup tile
constexpr int SP = 296;                     // Abuf row stride (bf16): 592B
// fragment-major weight layouts. Layers 1,2 use mfma_f32_32x32x16_bf16:
// A-frag mapping: lane l supplies A[m = l&31][k = (l>>5)*8 + j].
// Layer 3 keeps mfma_f32_16x16x32_bf16 (only 3 output rows).
constexpr int L1_KS = 18;                   // K=288 (266 padded), 16 per kstep
constexpr int L2_KS = 16;                   // K=256
constexpr int L1_FRAGS = L1_KS * 8 * 64;    // 9216
constexpr int L2_FRAGS = L2_KS * 8 * 64;    // 8192
constexpr int L3_FRAGS = 8 * 64;            // 512
constexpr int N_FRAGS = L1_FRAGS + L2_FRAGS + L3_FRAGS;   // 17920
constexpr int SC_OFF_BYTES = N_FRAGS * 16;                 // 286720
constexpr int B1EFF_OFF_BYTES = SC_OFF_BYTES + Bn * 3 * hn * wn * 4;
constexpr int FEATT_OFF_BYTES = B1EFF_OFF_BYTES + 1024;    // featT: [B][h][w][C] f32
constexpr int FRAG_BLOCKS = N_FRAGS / 256;  // 70
constexpr int SC_BLOCKS = (Bn * hn * wn) / 256;  // 72
}

// ---------------- prep (single dispatch): weight frags + b1eff + shortcut MLP + featT ----------------
__global__ void prep_all(const float* __restrict__ w00, const float* __restrict__ w1,
                         const float* __restrict__ w2, const float* __restrict__ b00,
                         const float* __restrict__ b1,
                         const float* __restrict__ feat, const float* __restrict__ ws1,
                         const float* __restrict__ bs1, const float* __restrict__ ws2,
                         const float* __restrict__ bs2,
                         __bf16* __restrict__ wb, float* __restrict__ b1eff,
                         float* __restrict__ sc, float* __restrict__ featT)
{
    const int bid = blockIdx.x;
    if (bid < FRAG_BLOCKS) {
        const int f = bid * 256 + threadIdx.x;
        bf16x8 v;
        if (f < L1_FRAGS) {
            const int fr = f >> 6;          // (ks*8 + mb)
            const int l  = f & 63;
            const int ks = fr >> 3;
            const int mb = fr & 7;
            const int m  = mb * 32 + (l & 31);
            const int kb = ks * 16 + (l >> 5) * 8;
#pragma unroll
            for (int j = 0; j < 8; j++)
                v[j] = (kb + j < CIN) ? (__bf16)w00[m * CIN + kb + j] : (__bf16)0.f;
        } else if (f < L1_FRAGS + L2_FRAGS) {
            const int g = f - L1_FRAGS;
            const int fr = g >> 6;
            const int l  = g & 63;
            const int ks = fr >> 3;
            const int mb = fr & 7;
            const int m  = mb * 32 + (l & 31);
            const int kb = ks * 16 + (l >> 5) * 8;
#pragma unroll
            for (int j = 0; j < 8; j++) v[j] = (__bf16)w1[m * 256 + kb + j];
        } else {
            // layer-3 frags keep the 16x16x32 A-layout: lane l -> m=l&15, k=(l>>4)*8+j
            const int g = f - (L1_FRAGS + L2_FRAGS);
            const int k0 = g >> 6;
            const int l  = g & 63;
            const int m  = l & 15;
            const int kb = k0 * 32 + (l >> 4) * 8;
#pragma unroll
            for (int j = 0; j < 8; j++)
                v[j] = (m < 3) ? (__bf16)w2[m * 256 + kb + j] : (__bf16)0.f;
        }
        *(bf16x8*)(wb + f * 8) = v;
        return;
    }
    if (bid == FRAG_BLOCKS) {
        // b1eff[o] = b1[o] + sum_c w1[o][c]*(b00[c] + 0.5*(w00[c][264]+w00[c][265]))
        __shared__ float cb[256];
        const int o = threadIdx.x;
        cb[o] = b00[o] + 0.5f * (w00[o * CIN + 264] + w00[o * CIN + 265]);
        __syncthreads();
        float v = b1[o];
#pragma unroll 4
        for (int k = 0; k < 256; k++) v = fmaf(w1[o * 256 + k], cb[k], v);
        b1eff[o] = v;
        return;
    }
    // shortcut MLP on LR grid; also emits the channel-last featT for the main gather
    const int t = (bid - FRAG_BLOCKS - 1) * 256 + threadIdx.x;
    if (t >= Bn * hn * wn) return;
    const int b = t / (hn * wn);
    const int yx = t % (hn * wn);
    const float* fp = feat + b * Cn * hn * wn + yx;
    float f[Cn];
#pragma unroll
    for (int c = 0; c < Cn; c++) f[c] = fp[c * hn * wn];
    // featT[b][y][x][c] = feat[b][c][y][x]  (t*64 is exactly ((b*h+y)*w+x)*64)
    {
        float* ft = featT + t * Cn;
#pragma unroll
        for (int c4 = 0; c4 < Cn / 4; c4++)
            *(f32x4*)&ft[c4 * 4] =
                (f32x4){f[4 * c4], f[4 * c4 + 1], f[4 * c4 + 2], f[4 * c4 + 3]};
    }
    float o0 = bs2[0], o1 = bs2[1], o2 = bs2[2];
#pragma unroll 1
    for (int co = 0; co < Cn; co += 4) {
        float v0 = bs1[co], v1 = bs1[co + 1], v2 = bs1[co + 2], v3 = bs1[co + 3];
        const float* wr = ws1 + co * Cn;
#pragma unroll
        for (int ci = 0; ci < Cn; ci++) {
            const float fv = f[ci];
            v0 = fmaf(wr[ci], fv, v0);
            v1 = fmaf(wr[Cn + ci], fv, v1);
            v2 = fmaf(wr[2 * Cn + ci], fv, v2);
            v3 = fmaf(wr[3 * Cn + ci], fv, v3);
        }
        v0 = fmaxf(v0, 0.f); v1 = fmaxf(v1, 0.f); v2 = fmaxf(v2, 0.f); v3 = fmaxf(v3, 0.f);
#pragma unroll
        for (int u = 0; u < 4; u++) {
            const float vv = (u == 0) ? v0 : (u == 1) ? v1 : (u == 2) ? v2 : v3;
            o0 = fmaf(ws2[co + u], vv, o0);
            o1 = fmaf(ws2[Cn + co + u], vv, o1);
            o2 = fmaf(ws2[2 * Cn + co + u], vv, o2);
        }
    }
    sc[(b * 3 + 0) * hn * wn + yx] = o0;
    sc[(b * 3 + 1) * hn * wn + yx] = o1;
    sc[(b * 3 + 2) * hn * wn + yx] = o2;
}

__device__ __forceinline__ float gelu_fast(float x) {
    // tanh-form gelu via sigmoid in exp2 domain: x * 1/(1 + 2^(x*(d0+d1*x^2)))
    const float d0 = -2.302118074f;   // -2*0.7978845608*log2(e)
    const float d1 = -0.1029453754f;  // -2*0.0356774081*log2(e)
    float t = x * x;
    float a = x * fmaf(t, d1, d0);
    float e = __builtin_amdgcn_exp2f(a);
    return x * __builtin_amdgcn_rcpf(1.f + e);
}

__device__ __forceinline__ bf16x4 pack4(f32x4 x) {
    bf16x4 v;
    v[0] = (__bf16)x[0]; v[1] = (__bf16)x[1]; v[2] = (__bf16)x[2]; v[3] = (__bf16)x[3];
    return v;
}

// ---------------- fused main kernel ----------------
// Operand-swapped GEMMs: D = W (A-operand, global->VGPR stream) x Act^T
// (B-operand from LDS). Hot path fully scalarized (R3/R4 lesson: any
// array/lambda indirection on the weight double-buffer defeats mem2reg).
// Layers 1,2 use 32x32x16 MFMA: same FLOPs at the higher 32x32 rate
// (2495 vs 2075 TF ceiling) and HALF the MFMA instruction count vs 16x16x32,
// freeing issue slots for the VALU-heavy gather/gelu phases.

#define MF16(A, B, C) __builtin_amdgcn_mfma_f32_16x16x32_bf16((A), (B), (C), 0, 0, 0)
#define MF32(A, B, C) __builtin_amdgcn_mfma_f32_32x32x16_bf16((A), (B), (C), 0, 0, 0)

// one 32x32x16 kstep: 2 weight mblocks (64 out-ch of this wave) x 2 pixel-blocks
#define G32(ks, W0, W1) do {                                                    \
    const bf16x8 g0 = *(const bf16x8*)&Abuf[     l31][(ks) * 16 + hh * 8];      \
    const bf16x8 g1 = *(const bf16x8*)&Abuf[32 + l31][(ks) * 16 + hh * 8];      \
    c00 = MF32(W0, g0, c00); c01 = MF32(W0, g1, c01);                           \
    c10 = MF32(W1, g0, c10); c11 = MF32(W1, g1, c11);                           \
} while (0)

#define LDW2(W0, W1, src, kk) do {                    \
    W0 = (src)[((kk) * 8 + mbp + 0) * 64 + lane];     \
    W1 = (src)[((kk) * 8 + mbp + 1) * 64 + lane];     \
} while (0)

// bf16x4 from f32x16 slice g (regs 4g..4g+3 = 4 consecutive channels)
#define PKS(v, g) pack4((f32x4){(v)[4 * (g)], (v)[4 * (g) + 1], (v)[4 * (g) + 2], (v)[4 * (g) + 3]})

__global__ __launch_bounds__(256, 3) void liif_main(
    const float* __restrict__ featT, const float* __restrict__ b1eff,
    const float* __restrict__ b2v, const __bf16* __restrict__ wb,
    const float* __restrict__ sc, float* __restrict__ out)
{
    __shared__ __align__(16) __bf16 Abuf[TM][SP];

    const int t = threadIdx.x;
    const int wv = t >> 6;
    const int lane = t & 63;
    const int lane16 = lane & 15;
    const int quad = lane >> 4;
    const int l31 = lane & 31;
    const int hh = lane >> 5;
    const int mbp = wv * 2;     // this wave's 32x32 mblock pair (channels wv*64..+63)

    // XCD swizzle: HW assigns XCD = blockIdx % 8; remap so each XCD owns a
    // contiguous Y-band (614 KB feat slice stays L2-resident).
    constexpr int NWG = Bn * Hn * (Wn / TM);       // 4608
    const int lt = (blockIdx.x & 7) * (NWG / 8) + (blockIdx.x >> 3);
    constexpr int TPR = Wn / TM;  // 6 tiles per HR row
    const int tx = lt % TPR;
    const int Y = (lt / TPR) % Hn;
    const int b = lt / (TPR * Hn);
    const int X0 = tx * TM;

    const float cy = -1.f + 1.f / Hn + (2.f / Hn) * (float)Y;

    const bf16x8* wf1 = (const bf16x8*)wb;
    const bf16x8* wf2 = wf1 + L1_FRAGS;
    const bf16x8* w2f = wf1 + (L1_FRAGS + L2_FRAGS);

    // layer-1 initial prefetch (ksteps 0,1) issued BEFORE the gather
    bf16x8 wE0, wE1, wO0, wO1;
    LDW2(wE0, wE1, wf1, 0);
    LDW2(wO0, wO1, wf1, 1);

    // ---------- phase 1: build grid features [64 x 266] bf16 in Abuf ----------
    {
        const int p = lane;     // pixel in tile
        const int j = wv;       // this wave handles corner j's gather
        const int X = X0 + p;
        const float cx = -1.f + 1.f / Wn + (2.f / Wn) * (float)X;
        float rely[4], relx[4], area[4];
        int iyv[4], ixv[4];
#pragma unroll
        for (int c = 0; c < 4; c++) {
            const float vx = (c & 2) ? 1.f : -1.f;   // shift along height
            const float vy = (c & 1) ? 1.f : -1.f;   // shift along width
            float sy = fminf(fmaxf(cy + vx * (1.f / hn) + 1e-6f, -1.f + 1e-6f), 1.f - 1e-6f);
            float sx = fminf(fmaxf(cx + vy * (1.f / wn) + 1e-6f, -1.f + 1e-6f), 1.f - 1e-6f);
            float uy = ((sy + 1.f) * hn - 1.f) * 0.5f;
            float ux = ((sx + 1.f) * wn - 1.f) * 0.5f;
            int iy = min(max((int)rintf(uy), 0), hn - 1);   // round-half-even == jnp.round
            int ix = min(max((int)rintf(ux), 0), wn - 1);
            float oy = -1.f + 1.f / hn + (2.f / hn) * (float)iy;
            float ox = -1.f + 1.f / wn + (2.f / wn) * (float)ix;
            rely[c] = (cy - oy) * hn;
            relx[c] = (cx - ox) * wn;
            area[c] = fabsf(rely[c] * relx[c]) + 1e-9f;
            iyv[c] = iy; ixv[c] = ix;
        }
        const float tot = area[0] + area[1] + area[2] + area[3];
        const float wj = area[3 - j] / tot;   // LIIF area swap 0<->3, 1<->2

        if (j == 0) {  // channels 0..7: [rel_y0, rel_x0, ..., rel_y3, rel_x3]
            bf16x8 v;
#pragma unroll
            for (int c = 0; c < 4; c++) { v[2 * c] = (__bf16)rely[c]; v[2 * c + 1] = (__bf16)relx[c]; }
            *(bf16x8*)&Abuf[p][0] = v;
        }
        // channels 8+64j .. 8+64j+63: feat at (iy_j, ix_j) scaled by wj
        // featT is channel-last: 64 consecutive f32 -> 16 dwordx4 loads
        const float* fb = featT + ((b * hn + iyv[j]) * wn + ixv[j]) * Cn;
#pragma unroll
        for (int c8 = 0; c8 < 8; c8++) {
            const f32x4 u0 = *(const f32x4*)&fb[c8 * 8];
            const f32x4 u1 = *(const f32x4*)&fb[c8 * 8 + 4];
            bf16x8 v;
            v[0] = (__bf16)(u0[0] * wj); v[1] = (__bf16)(u0[1] * wj);
            v[2] = (__bf16)(u0[2] * wj); v[3] = (__bf16)(u0[3] * wj);
            v[4] = (__bf16)(u1[0] * wj); v[5] = (__bf16)(u1[1] * wj);
            v[6] = (__bf16)(u1[2] * wj); v[7] = (__bf16)(u1[3] * wj);
            *(bf16x8*)&Abuf[p][8 + 64 * j + c8 * 8] = v;
        }
        if (j == 3) {  // channels 264..287 zero (rel_cell folded into b1eff)
            bf16x8 z;
#pragma unroll
            for (int cc = 0; cc < 8; cc++) z[cc] = (__bf16)0.f;
            *(bf16x8*)&Abuf[p][264] = z;
            *(bf16x8*)&Abuf[p][272] = z;
            *(bf16x8*)&Abuf[p][280] = z;
        }
    }
    __syncthreads();

    const f32x16 zf = {0.f, 0.f, 0.f, 0.f, 0.f, 0.f, 0.f, 0.f,
                       0.f, 0.f, 0.f, 0.f, 0.f, 0.f, 0.f, 0.f};
    f32x16 c00 = zf, c01 = zf, c10 = zf, c11 = zf;

    // ---------- layer 1: W00[256x288] x G^T, 18 ksteps of K=16 ----------
    G32(0,  wE0, wE1); LDW2(wE0, wE1, wf1, 2);
    G32(1,  wO0, wO1); LDW2(wO0, wO1, wf1, 3);
    G32(2,  wE0, wE1); LDW2(wE0, wE1, wf1, 4);
    G32(3,  wO0, wO1); LDW2(wO0, wO1, wf1, 5);
    G32(4,  wE0, wE1); LDW2(wE0, wE1, wf1, 6);
    G32(5,  wO0, wO1); LDW2(wO0, wO1, wf1, 7);
    G32(6,  wE0, wE1); LDW2(wE0, wE1, wf1, 8);
    G32(7,  wO0, wO1); LDW2(wO0, wO1, wf1, 9);
    G32(8,  wE0, wE1); LDW2(wE0, wE1, wf1, 10);
    G32(9,  wO0, wO1); LDW2(wO0, wO1, wf1, 11);
    G32(10, wE0, wE1); LDW2(wE0, wE1, wf1, 12);
    G32(11, wO0, wO1); LDW2(wO0, wO1, wf1, 13);
    G32(12, wE0, wE1); LDW2(wE0, wE1, wf1, 14);
    G32(13, wO0, wO1); LDW2(wO0, wO1, wf1, 15);
    G32(14, wE0, wE1); LDW2(wE0, wE1, wf1, 16);
    G32(15, wO0, wO1); LDW2(wO0, wO1, wf1, 17);
    G32(16, wE0, wE1); LDW2(wE0, wE1, wf2, 0);   // next layer k0
    G32(17, wO0, wO1); LDW2(wO0, wO1, wf2, 1);   // next layer k1

    __syncthreads();  // all grid readers done before overwriting Abuf with X
    // epilogue 1: no bias (b00 + rel_cell folded into b1eff); packed b64 writes
    // C layout (32x32): pixel = ni*32 + l31, channel = wv*64 + mi*32 + hh*4 + g*8 + (reg&3)
    {
        const int colA = wv * 64 + hh * 4;
        const int rA = l31;
        *(bf16x4*)&Abuf[rA     ][colA +  0] = PKS(c00, 0);
        *(bf16x4*)&Abuf[rA     ][colA +  8] = PKS(c00, 1);
        *(bf16x4*)&Abuf[rA     ][colA + 16] = PKS(c00, 2);
        *(bf16x4*)&Abuf[rA     ][colA + 24] = PKS(c00, 3);
        *(bf16x4*)&Abuf[rA + 32][colA +  0] = PKS(c01, 0);
        *(bf16x4*)&Abuf[rA + 32][colA +  8] = PKS(c01, 1);
        *(bf16x4*)&Abuf[rA + 32][colA + 16] = PKS(c01, 2);
        *(bf16x4*)&Abuf[rA + 32][colA + 24] = PKS(c01, 3);
        *(bf16x4*)&Abuf[rA     ][colA + 32] = PKS(c10, 0);
        *(bf16x4*)&Abuf[rA     ][colA + 40] = PKS(c10, 1);
        *(bf16x4*)&Abuf[rA     ][colA + 48] = PKS(c10, 2);
        *(bf16x4*)&Abuf[rA     ][colA + 56] = PKS(c10, 3);
        *(bf16x4*)&Abuf[rA + 32][colA + 32] = PKS(c11, 0);
        *(bf16x4*)&Abuf[rA + 32][colA + 40] = PKS(c11, 1);
        *(bf16x4*)&Abuf[rA + 32][colA + 48] = PKS(c11, 2);
        *(bf16x4*)&Abuf[rA + 32][colA + 56] = PKS(c11, 3);
    }
    __syncthreads();

    c00 = zf; c01 = zf; c10 = zf; c11 = zf;

    // ---------- layer 2: W1[256x256] x X, 16 ksteps of K=16 ----------
    G32(0,  wE0, wE1); LDW2(wE0, wE1, wf2, 2);
    G32(1,  wO0, wO1); LDW2(wO0, wO1, wf2, 3);
    G32(2,  wE0, wE1); LDW2(wE0, wE1, wf2, 4);
    G32(3,  wO0, wO1); LDW2(wO0, wO1, wf2, 5);
    G32(4,  wE0, wE1); LDW2(wE0, wE1, wf2, 6);
    G32(5,  wO0, wO1); LDW2(wO0, wO1, wf2, 7);
    G32(6,  wE0, wE1); LDW2(wE0, wE1, wf2, 8);
    G32(7,  wO0, wO1); LDW2(wO0, wO1, wf2, 9);
    G32(8,  wE0, wE1); LDW2(wE0, wE1, wf2, 10);
    G32(9,  wO0, wO1); LDW2(wO0, wO1, wf2, 11);
    G32(10, wE0, wE1); LDW2(wE0, wE1, wf2, 12);
    G32(11, wO0, wO1); LDW2(wO0, wO1, wf2, 13);
    G32(12, wE0, wE1); LDW2(wE0, wE1, wf2, 14);
    G32(13, wO0, wO1); LDW2(wO0, wO1, wf2, 15);
    G32(14, wE0, wE1); wE0 = w2f[0 * 64 + lane];   // w2 k0 (16x16 frag)
    G32(15, wO0, wO1); wE1 = w2f[1 * 64 + lane];   // w2 k1

    __syncthreads();
    // epilogue 2: bias + gelu, packed b64 writes
    {
        const int colA = wv * 64 + hh * 4;
        const int rA = l31;
        bf16x4 vv;
        f32x4 bi;
#define GEL4S(v, g, bi) { bf16x4 w_; \
        w_[0] = (__bf16)gelu_fast((v)[4 * (g) + 0] + (bi)[0]); \
        w_[1] = (__bf16)gelu_fast((v)[4 * (g) + 1] + (bi)[1]); \
        w_[2] = (__bf16)gelu_fast((v)[4 * (g) + 2] + (bi)[2]); \
        w_[3] = (__bf16)gelu_fast((v)[4 * (g) + 3] + (bi)[3]); vv = w_; }
        bi = *(const f32x4*)&b1eff[colA + 0];
        GEL4S(c00, 0, bi); *(bf16x4*)&Abuf[rA     ][colA +  0] = vv;
        GEL4S(c01, 0, bi); *(bf16x4*)&Abuf[rA + 32][colA +  0] = vv;
        bi = *(const f32x4*)&b1eff[colA + 8];
        GEL4S(c00, 1, bi); *(bf16x4*)&Abuf[rA     ][colA +  8] = vv;
        GEL4S(c01, 1, bi); *(bf16x4*)&Abuf[rA + 32][colA +  8] = vv;
        bi = *(const f32x4*)&b1eff[colA + 16];
        GEL4S(c00, 2, bi); *(bf16x4*)&Abuf[rA     ][colA + 16] = vv;
        GEL4S(c01, 2, bi); *(bf16x4*)&Abuf[rA + 32][colA + 16] = vv;
        bi = *(const f32x4*)&b1eff[colA + 24];
        GEL4S(c00, 3, bi); *(bf16x4*)&Abuf[rA     ][colA + 24] = vv;
        GEL4S(c01, 3, bi); *(bf16x4*)&Abuf[rA + 32][colA + 24] = vv;
        bi = *(const f32x4*)&b1eff[colA + 32];
        GEL4S(c10, 0, bi); *(bf16x4*)&Abuf[rA     ][colA + 32] = vv;
        GEL4S(c11, 0, bi); *(bf16x4*)&Abuf[rA + 32][colA + 32] = vv;
        bi = *(const f32x4*)&b1eff[colA + 40];
        GEL4S(c10, 1, bi); *(bf16x4*)&Abuf[rA     ][colA + 40] = vv;
        GEL4S(c11, 1, bi); *(bf16x4*)&Abuf[rA + 32][colA + 40] = vv;
        bi = *(const f32x4*)&b1eff[colA + 48];
        GEL4S(c10, 2, bi); *(bf16x4*)&Abuf[rA     ][colA + 48] = vv;
        GEL4S(c11, 2, bi); *(bf16x4*)&Abuf[rA + 32][colA + 48] = vv;
        bi = *(const f32x4*)&b1eff[colA + 56];
        GEL4S(c10, 3, bi); *(bf16x4*)&Abuf[rA     ][colA + 56] = vv;
        GEL4S(c11, 3, bi); *(bf16x4*)&Abuf[rA + 32][colA + 56] = vv;
#undef GEL4S
    }
    __syncthreads();

    // ---------- layer 3: W2[16x256] x Y, 8 ksteps of K=32 (16x16x32); wave wv owns pixel-block wv ----------
    const f32x4 zf4 = (f32x4){0.f, 0.f, 0.f, 0.f};
    f32x4 acc3 = zf4;
#define YF(k0) (*(const bf16x8*)&Abuf[wv * 16 + lane16][(k0) * 32 + quad * 8])
    acc3 = MF16(wE0, YF(0), acc3); wE0 = w2f[2 * 64 + lane];
    acc3 = MF16(wE1, YF(1), acc3); wE1 = w2f[3 * 64 + lane];
    acc3 = MF16(wE0, YF(2), acc3); wE0 = w2f[4 * 64 + lane];
    acc3 = MF16(wE1, YF(3), acc3); wE1 = w2f[5 * 64 + lane];
    acc3 = MF16(wE0, YF(4), acc3); wE0 = w2f[6 * 64 + lane];
    acc3 = MF16(wE1, YF(5), acc3); wE1 = w2f[7 * 64 + lane];
    acc3 = MF16(wE0, YF(6), acc3);
    acc3 = MF16(wE1, YF(7), acc3);
#undef YF

    // ---------- epilogue: rows 0..2 (quad 0) hold the 3 output channels ----------
    if (quad == 0) {
        const int pix = wv * 16 + lane16;
        const int X = X0 + pix;
        const float uy = ((cy + 1.f) * hn - 1.f) * 0.5f;
        const float fy = floorf(uy);
        const float wy = uy - fy;
        const int y0i = min(max((int)fy, 0), hn - 1);
        const int y1i = min(max((int)fy + 1, 0), hn - 1);
        const float cx = -1.f + 1.f / Wn + (2.f / Wn) * (float)X;
        const float ux = ((cx + 1.f) * wn - 1.f) * 0.5f;
        const float fx = floorf(ux);
        const float wx = ux - fx;
        const int x0i = min(max((int)fx, 0), wn - 1);
        const int x1i = min(max((int)fx + 1, 0), wn - 1);
        const float w00b = (1.f - wy) * (1.f - wx), w01b = (1.f - wy) * wx;
        const float w10b = wy * (1.f - wx), w11b = wy * wx;
#pragma unroll
        for (int r = 0; r < 3; r++) {
            const float* scb = sc + (b * 3 + r) * (hn * wn);
            const float samp = scb[y0i * wn + x0i] * w00b + scb[y0i * wn + x1i] * w01b
                             + scb[y1i * wn + x0i] * w10b + scb[y1i * wn + x1i] * w11b;
            out[((b * 3 + r) * Hn + Y) * Wn + X] = acc3[r] + b2v[r] + samp;
        }
    }
}

extern "C" void kernel_launch(void* const* d_in, const int* in_sizes, int n_in,
                              void* d_out, int out_size, void* d_ws, size_t ws_size,
                              hipStream_t stream)
{
    const float* feat = (const float*)d_in[0];
    const float* w00  = (const float*)d_in[1];
    const float* b00  = (const float*)d_in[2];
    const float* w1   = (const float*)d_in[3];
    const float* b1   = (const float*)d_in[4];
    const float* w2   = (const float*)d_in[5];
    const float* b2   = (const float*)d_in[6];
    const float* ws1  = (const float*)d_in[7];
    const float* bs1  = (const float*)d_in[8];
    const float* ws2  = (const float*)d_in[9];
    const float* bs2  = (const float*)d_in[10];
    float* out = (float*)d_out;

    __bf16* wb    = (__bf16*)d_ws;
    float* scbuf  = (float*)((char*)d_ws + SC_OFF_BYTES);
    float* b1eff  = (float*)((char*)d_ws + B1EFF_OFF_BYTES);
    float* featT  = (float*)((char*)d_ws + FEATT_OFF_BYTES);

    prep_all<<<FRAG_BLOCKS + 1 + SC_BLOCKS, 256, 0, stream>>>(
        w00, w1, w2, b00, b1, feat, ws1, bs1, ws2, bs2, wb, b1eff, scbuf, featT);
    liif_main<<<Bn * Hn * (Wn / TM), 256, 0, stream>>>(featT, b1eff, b2, wb, scbuf, out);
}

// Round 2
// 205.951 us; speedup vs baseline: 1.0456x; 1.0456x over previous
//
#include <hip/hip_runtime.h>

typedef __bf16 bf16x8 __attribute__((ext_vector_type(8)));
typedef __bf16 bf16x4 __attribute__((ext_vector_type(4)));
typedef float f32x4 __attribute__((ext_vector_type(4)));

namespace {
constexpr int Bn = 2, Cn = 64, hn = 96, wn = 96, Hn = 384, Wn = 384;
constexpr int CIN = 266;
constexpr int TM = 64;                      // pixels per workgroup tile
constexpr int SP = 296;                     // Abuf row stride (bf16): 592B
// fragment-major weight layouts. A-frag mapping for mfma_f32_16x16x32_bf16:
// lane l supplies A[m = l&15][k = (l>>4)*8 + j].
constexpr int L1_FRAGS = 9 * 16 * 64;       // 9216
constexpr int L2_FRAGS = 8 * 16 * 64;       // 8192
constexpr int L3_FRAGS = 8 * 64;            // 512
constexpr int N_FRAGS = L1_FRAGS + L2_FRAGS + L3_FRAGS;   // 17920
constexpr int SC_OFF_BYTES = N_FRAGS * 16;                 // 286720
constexpr int B1EFF_OFF_BYTES = SC_OFF_BYTES + Bn * 3 * hn * wn * 4;
constexpr int FEATT_OFF_BYTES = B1EFF_OFF_BYTES + 1024;    // featT: [B][h][w][C] f32
constexpr int FRAG_BLOCKS = N_FRAGS / 256;  // 70
constexpr int SC_BLOCKS = (Bn * hn * wn) / 256;  // 72
}

// ---------------- prep (single dispatch): weight frags + b1eff + shortcut MLP + featT ----------------
__global__ void prep_all(const float* __restrict__ w00, const float* __restrict__ w1,
                         const float* __restrict__ w2, const float* __restrict__ b00,
                         const float* __restrict__ b1,
                         const float* __restrict__ feat, const float* __restrict__ ws1,
                         const float* __restrict__ bs1, const float* __restrict__ ws2,
                         const float* __restrict__ bs2,
                         __bf16* __restrict__ wb, float* __restrict__ b1eff,
                         float* __restrict__ sc, float* __restrict__ featT)
{
    const int bid = blockIdx.x;
    if (bid < FRAG_BLOCKS) {
        const int f = bid * 256 + threadIdx.x;
        bf16x8 v;
        if (f < L1_FRAGS) {
            const int k0 = f >> 10;
            const int mb = (f >> 6) & 15;
            const int l  = f & 63;
            const int m  = mb * 16 + (l & 15);
            const int kb = k0 * 32 + (l >> 4) * 8;
#pragma unroll
            for (int j = 0; j < 8; j++)
                v[j] = (kb + j < CIN) ? (__bf16)w00[m * CIN + kb + j] : (__bf16)0.f;
        } else if (f < L1_FRAGS + L2_FRAGS) {
            const int g = f - L1_FRAGS;
            const int k0 = g >> 10;
            const int mb = (g >> 6) & 15;
            const int l  = g & 63;
            const int m  = mb * 16 + (l & 15);
            const int kb = k0 * 32 + (l >> 4) * 8;
#pragma unroll
            for (int j = 0; j < 8; j++) v[j] = (__bf16)w1[m * 256 + kb + j];
        } else {
            const int g = f - (L1_FRAGS + L2_FRAGS);
            const int k0 = g >> 6;
            const int l  = g & 63;
            const int m  = l & 15;
            const int kb = k0 * 32 + (l >> 4) * 8;
#pragma unroll
            for (int j = 0; j < 8; j++)
                v[j] = (m < 3) ? (__bf16)w2[m * 256 + kb + j] : (__bf16)0.f;
        }
        *(bf16x8*)(wb + f * 8) = v;
        return;
    }
    if (bid == FRAG_BLOCKS) {
        // b1eff[o] = b1[o] + sum_c w1[o][c]*(b00[c] + 0.5*(w00[c][264]+w00[c][265]))
        __shared__ float cb[256];
        const int o = threadIdx.x;
        cb[o] = b00[o] + 0.5f * (w00[o * CIN + 264] + w00[o * CIN + 265]);
        __syncthreads();
        float v = b1[o];
#pragma unroll 4
        for (int k = 0; k < 256; k++) v = fmaf(w1[o * 256 + k], cb[k], v);
        b1eff[o] = v;
        return;
    }
    // shortcut MLP on LR grid; also emits the channel-last featT for the main gather
    const int t = (bid - FRAG_BLOCKS - 1) * 256 + threadIdx.x;
    if (t >= Bn * hn * wn) return;
    const int b = t / (hn * wn);
    const int yx = t % (hn * wn);
    const float* fp = feat + b * Cn * hn * wn + yx;
    float f[Cn];
#pragma unroll
    for (int c = 0; c < Cn; c++) f[c] = fp[c * hn * wn];
    // featT[b][y][x][c] = feat[b][c][y][x]  (t*64 is exactly ((b*h+y)*w+x)*64)
    {
        float* ft = featT + t * Cn;
#pragma unroll
        for (int c4 = 0; c4 < Cn / 4; c4++)
            *(f32x4*)&ft[c4 * 4] =
                (f32x4){f[4 * c4], f[4 * c4 + 1], f[4 * c4 + 2], f[4 * c4 + 3]};
    }
    float o0 = bs2[0], o1 = bs2[1], o2 = bs2[2];
#pragma unroll 1
    for (int co = 0; co < Cn; co += 4) {
        float v0 = bs1[co], v1 = bs1[co + 1], v2 = bs1[co + 2], v3 = bs1[co + 3];
        const float* wr = ws1 + co * Cn;
#pragma unroll
        for (int ci = 0; ci < Cn; ci++) {
            const float fv = f[ci];
            v0 = fmaf(wr[ci], fv, v0);
            v1 = fmaf(wr[Cn + ci], fv, v1);
            v2 = fmaf(wr[2 * Cn + ci], fv, v2);
            v3 = fmaf(wr[3 * Cn + ci], fv, v3);
        }
        v0 = fmaxf(v0, 0.f); v1 = fmaxf(v1, 0.f); v2 = fmaxf(v2, 0.f); v3 = fmaxf(v3, 0.f);
#pragma unroll
        for (int u = 0; u < 4; u++) {
            const float vv = (u == 0) ? v0 : (u == 1) ? v1 : (u == 2) ? v2 : v3;
            o0 = fmaf(ws2[co + u], vv, o0);
            o1 = fmaf(ws2[Cn + co + u], vv, o1);
            o2 = fmaf(ws2[2 * Cn + co + u], vv, o2);
        }
    }
    sc[(b * 3 + 0) * hn * wn + yx] = o0;
    sc[(b * 3 + 1) * hn * wn + yx] = o1;
    sc[(b * 3 + 2) * hn * wn + yx] = o2;
}

__device__ __forceinline__ float gelu_fast(float x) {
    // tanh-form gelu via sigmoid in exp2 domain: x * 1/(1 + 2^(x*(d0+d1*x^2)))
    const float d0 = -2.302118074f;   // -2*0.7978845608*log2(e)
    const float d1 = -0.1029453754f;  // -2*0.0356774081*log2(e)
    float t = x * x;
    float a = x * fmaf(t, d1, d0);
    float e = __builtin_amdgcn_exp2f(a);
    return x * __builtin_amdgcn_rcpf(1.f + e);
}

__device__ __forceinline__ bf16x4 pack4(f32x4 x) {
    bf16x4 v;
    v[0] = (__bf16)x[0]; v[1] = (__bf16)x[1]; v[2] = (__bf16)x[2]; v[3] = (__bf16)x[3];
    return v;
}

// ---------------- fused main kernel ----------------
// Operand-swapped GEMMs: D = W (A-operand, global->VGPR stream) x Act^T
// (B-operand from LDS). R3/R4 lesson: ANY array/lambda indirection on the
// weight double-buffer defeats mem2reg -> scratch-resident buffer -> ~40-60MB
// of HBM scratch traffic + per-kstep vmcnt serialization. So the hot path is
// fully scalarized: named bf16x8 scalars wE0..3 / wO0..3 (even/odd ksteps),
// named f32x4 accumulators, hand-unrolled macros, GSTEP-before-load ordering
// (WAR keeps the distance-2 prefetch behind the consuming MFMAs).
// R1 lesson: 32x32x16 MFMA (4 MFMAs/kstep) starves the latency-hiding --
// per-kstep compute blocks must stay ~16 MFMAs to cover ds_read+global latency.

#define MF(A, B, C) __builtin_amdgcn_mfma_f32_16x16x32_bf16((A), (B), (C), 0, 0, 0)

// 16 MFMAs of one kstep: weights W0..W3 (mblocks mb0..mb0+3) x 4 pixel-blocks
#define GSTEP(k0, W0, W1, W2, W3) do {                                          \
    const bf16x8 g0 = *(const bf16x8*)&Abuf[     lane16][(k0) * 32 + quad * 8]; \
    const bf16x8 g1 = *(const bf16x8*)&Abuf[16 + lane16][(k0) * 32 + quad * 8]; \
    const bf16x8 g2 = *(const bf16x8*)&Abuf[32 + lane16][(k0) * 32 + quad * 8]; \
    const bf16x8 g3 = *(const bf16x8*)&Abuf[48 + lane16][(k0) * 32 + quad * 8]; \
    a00 = MF(W0, g0, a00); a01 = MF(W1, g0, a01); a02 = MF(W2, g0, a02); a03 = MF(W3, g0, a03); \
    a10 = MF(W0, g1, a10); a11 = MF(W1, g1, a11); a12 = MF(W2, g1, a12); a13 = MF(W3, g1, a13); \
    a20 = MF(W0, g2, a20); a21 = MF(W1, g2, a21); a22 = MF(W2, g2, a22); a23 = MF(W3, g2, a23); \
    a30 = MF(W0, g3, a30); a31 = MF(W1, g3, a31); a32 = MF(W2, g3, a32); a33 = MF(W3, g3, a33); \
} while (0)

#define LDW(W0, W1, W2, W3, src, kk) do {             \
    W0 = (src)[((kk) * 16 + mb0 + 0) * 64 + lane];    \
    W1 = (src)[((kk) * 16 + mb0 + 1) * 64 + lane];    \
    W2 = (src)[((kk) * 16 + mb0 + 2) * 64 + lane];    \
    W3 = (src)[((kk) * 16 + mb0 + 3) * 64 + lane];    \
} while (0)

#define ZACC4(n) a##n##0 = zf; a##n##1 = zf; a##n##2 = zf; a##n##3 = zf

__global__ __launch_bounds__(256, 3) void liif_main(
    const float* __restrict__ featT, const float* __restrict__ b1eff,
    const float* __restrict__ b2v, const __bf16* __restrict__ wb,
    const float* __restrict__ sc, float* __restrict__ out)
{
    __shared__ __align__(16) __bf16 Abuf[TM][SP];

    const int t = threadIdx.x;
    const int wv = t >> 6;
    const int lane = t & 63;
    const int lane16 = lane & 15;
    const int quad = lane >> 4;
    const int mb0 = wv * 4;

    // XCD swizzle: HW assigns XCD = blockIdx % 8; remap so each XCD owns a
    // contiguous Y-band (614 KB feat slice stays L2-resident). FETCH 26->10MB.
    constexpr int NWG = Bn * Hn * (Wn / TM);       // 4608
    const int lt = (blockIdx.x & 7) * (NWG / 8) + (blockIdx.x >> 3);
    constexpr int TPR = Wn / TM;  // 6 tiles per HR row
    const int tx = lt % TPR;
    const int Y = (lt / TPR) % Hn;
    const int b = lt / (TPR * Hn);
    const int X0 = tx * TM;

    const float cy = -1.f + 1.f / Hn + (2.f / Hn) * (float)Y;

    const bf16x8* wf1 = (const bf16x8*)wb;
    const bf16x8* wf2 = wf1 + L1_FRAGS;
    const bf16x8* w2f = wf1 + (L1_FRAGS + L2_FRAGS);

    // layer-1 initial prefetch (ksteps 0,1) issued BEFORE the gather
    bf16x8 wE0, wE1, wE2, wE3, wO0, wO1, wO2, wO3;
    LDW(wE0, wE1, wE2, wE3, wf1, 0);
    LDW(wO0, wO1, wO2, wO3, wf1, 1);

    // ---------- phase 1: build grid features [64 x 266] bf16 in Abuf ----------
    {
        const int p = lane;     // pixel in tile
        const int j = wv;       // this wave handles corner j's gather
        const int X = X0 + p;
        const float cx = -1.f + 1.f / Wn + (2.f / Wn) * (float)X;
        float rely[4], relx[4], area[4];
        int iyv[4], ixv[4];
#pragma unroll
        for (int c = 0; c < 4; c++) {
            const float vx = (c & 2) ? 1.f : -1.f;   // shift along height
            const float vy = (c & 1) ? 1.f : -1.f;   // shift along width
            float sy = fminf(fmaxf(cy + vx * (1.f / hn) + 1e-6f, -1.f + 1e-6f), 1.f - 1e-6f);
            float sx = fminf(fmaxf(cx + vy * (1.f / wn) + 1e-6f, -1.f + 1e-6f), 1.f - 1e-6f);
            float uy = ((sy + 1.f) * hn - 1.f) * 0.5f;
            float ux = ((sx + 1.f) * wn - 1.f) * 0.5f;
            int iy = min(max((int)rintf(uy), 0), hn - 1);   // round-half-even == jnp.round
            int ix = min(max((int)rintf(ux), 0), wn - 1);
            float oy = -1.f + 1.f / hn + (2.f / hn) * (float)iy;
            float ox = -1.f + 1.f / wn + (2.f / wn) * (float)ix;
            rely[c] = (cy - oy) * hn;
            relx[c] = (cx - ox) * wn;
            area[c] = fabsf(rely[c] * relx[c]) + 1e-9f;
            iyv[c] = iy; ixv[c] = ix;
        }
        const float tot = area[0] + area[1] + area[2] + area[3];
        const float wj = area[3 - j] / tot;   // LIIF area swap 0<->3, 1<->2

        if (j == 0) {  // channels 0..7: [rel_y0, rel_x0, ..., rel_y3, rel_x3]
            bf16x8 v;
#pragma unroll
            for (int c = 0; c < 4; c++) { v[2 * c] = (__bf16)rely[c]; v[2 * c + 1] = (__bf16)relx[c]; }
            *(bf16x8*)&Abuf[p][0] = v;
        }
        // channels 8+64j .. 8+64j+63: feat at (iy_j, ix_j) scaled by wj
        // featT is channel-last: 64 consecutive f32 -> 16 dwordx4 loads
        const float* fb = featT + ((b * hn + iyv[j]) * wn + ixv[j]) * Cn;
#pragma unroll
        for (int c8 = 0; c8 < 8; c8++) {
            const f32x4 u0 = *(const f32x4*)&fb[c8 * 8];
            const f32x4 u1 = *(const f32x4*)&fb[c8 * 8 + 4];
            bf16x8 v;
            v[0] = (__bf16)(u0[0] * wj); v[1] = (__bf16)(u0[1] * wj);
            v[2] = (__bf16)(u0[2] * wj); v[3] = (__bf16)(u0[3] * wj);
            v[4] = (__bf16)(u1[0] * wj); v[5] = (__bf16)(u1[1] * wj);
            v[6] = (__bf16)(u1[2] * wj); v[7] = (__bf16)(u1[3] * wj);
            *(bf16x8*)&Abuf[p][8 + 64 * j + c8 * 8] = v;
        }
        if (j == 3) {  // channels 264..287 zero (rel_cell folded into b1eff)
            bf16x8 z;
#pragma unroll
            for (int cc = 0; cc < 8; cc++) z[cc] = (__bf16)0.f;
            *(bf16x8*)&Abuf[p][264] = z;
            *(bf16x8*)&Abuf[p][272] = z;
            *(bf16x8*)&Abuf[p][280] = z;
        }
    }
    __syncthreads();

    const f32x4 zf = (f32x4){0.f, 0.f, 0.f, 0.f};
    f32x4 a00, a01, a02, a03, a10, a11, a12, a13;
    f32x4 a20, a21, a22, a23, a30, a31, a32, a33;
    ZACC4(0); ZACC4(1); ZACC4(2); ZACC4(3);

    // ---------- layer 1: W00[256x288] x G^T, 9 ksteps ----------
    GSTEP(0, wE0, wE1, wE2, wE3); LDW(wE0, wE1, wE2, wE3, wf1, 2);
    GSTEP(1, wO0, wO1, wO2, wO3); LDW(wO0, wO1, wO2, wO3, wf1, 3);
    GSTEP(2, wE0, wE1, wE2, wE3); LDW(wE0, wE1, wE2, wE3, wf1, 4);
    GSTEP(3, wO0, wO1, wO2, wO3); LDW(wO0, wO1, wO2, wO3, wf1, 5);
    GSTEP(4, wE0, wE1, wE2, wE3); LDW(wE0, wE1, wE2, wE3, wf1, 6);
    GSTEP(5, wO0, wO1, wO2, wO3); LDW(wO0, wO1, wO2, wO3, wf1, 7);
    GSTEP(6, wE0, wE1, wE2, wE3); LDW(wE0, wE1, wE2, wE3, wf1, 8);
    GSTEP(7, wO0, wO1, wO2, wO3); LDW(wO0, wO1, wO2, wO3, wf2, 0);  // next layer k0
    GSTEP(8, wE0, wE1, wE2, wE3); LDW(wE0, wE1, wE2, wE3, wf2, 1);  // next layer k1

    __syncthreads();  // all grid readers done before overwriting Abuf with X
    // epilogue 1: no bias (b00 + rel_cell folded into b1eff); packed b64 writes
    {
        const int ch0 = mb0 * 16 + quad * 4;
        *(bf16x4*)&Abuf[     lane16][ch0     ] = pack4(a00);
        *(bf16x4*)&Abuf[16 + lane16][ch0     ] = pack4(a10);
        *(bf16x4*)&Abuf[32 + lane16][ch0     ] = pack4(a20);
        *(bf16x4*)&Abuf[48 + lane16][ch0     ] = pack4(a30);
        *(bf16x4*)&Abuf[     lane16][ch0 + 16] = pack4(a01);
        *(bf16x4*)&Abuf[16 + lane16][ch0 + 16] = pack4(a11);
        *(bf16x4*)&Abuf[32 + lane16][ch0 + 16] = pack4(a21);
        *(bf16x4*)&Abuf[48 + lane16][ch0 + 16] = pack4(a31);
        *(bf16x4*)&Abuf[     lane16][ch0 + 32] = pack4(a02);
        *(bf16x4*)&Abuf[16 + lane16][ch0 + 32] = pack4(a12);
        *(bf16x4*)&Abuf[32 + lane16][ch0 + 32] = pack4(a22);
        *(bf16x4*)&Abuf[48 + lane16][ch0 + 32] = pack4(a32);
        *(bf16x4*)&Abuf[     lane16][ch0 + 48] = pack4(a03);
        *(bf16x4*)&Abuf[16 + lane16][ch0 + 48] = pack4(a13);
        *(bf16x4*)&Abuf[32 + lane16][ch0 + 48] = pack4(a23);
        *(bf16x4*)&Abuf[48 + lane16][ch0 + 48] = pack4(a33);
    }
    __syncthreads();

    ZACC4(0); ZACC4(1); ZACC4(2); ZACC4(3);

    // ---------- layer 2: W1[256x256] x X, 8 ksteps (k0 in wO, k1 in wE) ----------
    GSTEP(0, wO0, wO1, wO2, wO3); LDW(wO0, wO1, wO2, wO3, wf2, 2);
    GSTEP(1, wE0, wE1, wE2, wE3); LDW(wE0, wE1, wE2, wE3, wf2, 3);
    GSTEP(2, wO0, wO1, wO2, wO3); LDW(wO0, wO1, wO2, wO3, wf2, 4);
    GSTEP(3, wE0, wE1, wE2, wE3); LDW(wE0, wE1, wE2, wE3, wf2, 5);
    GSTEP(4, wO0, wO1, wO2, wO3); LDW(wO0, wO1, wO2, wO3, wf2, 6);
    GSTEP(5, wE0, wE1, wE2, wE3); LDW(wE0, wE1, wE2, wE3, wf2, 7);
    GSTEP(6, wO0, wO1, wO2, wO3); wO0 = w2f[0 * 64 + lane];          // w2 k0
    GSTEP(7, wE0, wE1, wE2, wE3); wE0 = w2f[1 * 64 + lane];          // w2 k1

    __syncthreads();
    // epilogue 2: bias + gelu, packed b64 writes
    {
        const int ch0 = mb0 * 16 + quad * 4;
        const f32x4 bi0 = *(const f32x4*)&b1eff[ch0];
        const f32x4 bi1 = *(const f32x4*)&b1eff[ch0 + 16];
        const f32x4 bi2 = *(const f32x4*)&b1eff[ch0 + 32];
        const f32x4 bi3 = *(const f32x4*)&b1eff[ch0 + 48];
#define GEL4(x, bi) { bf16x4 v; v[0] = (__bf16)gelu_fast((x)[0] + (bi)[0]); \
        v[1] = (__bf16)gelu_fast((x)[1] + (bi)[1]); \
        v[2] = (__bf16)gelu_fast((x)[2] + (bi)[2]); \
        v[3] = (__bf16)gelu_fast((x)[3] + (bi)[3]); vv = v; }
        bf16x4 vv;
        GEL4(a00, bi0); *(bf16x4*)&Abuf[     lane16][ch0     ] = vv;
        GEL4(a10, bi0); *(bf16x4*)&Abuf[16 + lane16][ch0     ] = vv;
        GEL4(a20, bi0); *(bf16x4*)&Abuf[32 + lane16][ch0     ] = vv;
        GEL4(a30, bi0); *(bf16x4*)&Abuf[48 + lane16][ch0     ] = vv;
        GEL4(a01, bi1); *(bf16x4*)&Abuf[     lane16][ch0 + 16] = vv;
        GEL4(a11, bi1); *(bf16x4*)&Abuf[16 + lane16][ch0 + 16] = vv;
        GEL4(a21, bi1); *(bf16x4*)&Abuf[32 + lane16][ch0 + 16] = vv;
        GEL4(a31, bi1); *(bf16x4*)&Abuf[48 + lane16][ch0 + 16] = vv;
        GEL4(a02, bi2); *(bf16x4*)&Abuf[     lane16][ch0 + 32] = vv;
        GEL4(a12, bi2); *(bf16x4*)&Abuf[16 + lane16][ch0 + 32] = vv;
        GEL4(a22, bi2); *(bf16x4*)&Abuf[32 + lane16][ch0 + 32] = vv;
        GEL4(a32, bi2); *(bf16x4*)&Abuf[48 + lane16][ch0 + 32] = vv;
        GEL4(a03, bi3); *(bf16x4*)&Abuf[     lane16][ch0 + 48] = vv;
        GEL4(a13, bi3); *(bf16x4*)&Abuf[16 + lane16][ch0 + 48] = vv;
        GEL4(a23, bi3); *(bf16x4*)&Abuf[32 + lane16][ch0 + 48] = vv;
        GEL4(a33, bi3); *(bf16x4*)&Abuf[48 + lane16][ch0 + 48] = vv;
#undef GEL4
    }
    __syncthreads();

    // ---------- layer 3: W2[16x256] x Y, 8 ksteps; wave wv owns pixel-block wv ----------
    f32x4 acc3 = zf;
#define YF(k0) (*(const bf16x8*)&Abuf[wv * 16 + lane16][(k0) * 32 + quad * 8])
    acc3 = MF(wO0, YF(0), acc3); wO0 = w2f[2 * 64 + lane];
    acc3 = MF(wE0, YF(1), acc3); wE0 = w2f[3 * 64 + lane];
    acc3 = MF(wO0, YF(2), acc3); wO0 = w2f[4 * 64 + lane];
    acc3 = MF(wE0, YF(3), acc3); wE0 = w2f[5 * 64 + lane];
    acc3 = MF(wO0, YF(4), acc3); wO0 = w2f[6 * 64 + lane];
    acc3 = MF(wE0, YF(5), acc3); wE0 = w2f[7 * 64 + lane];
    acc3 = MF(wO0, YF(6), acc3);
    acc3 = MF(wE0, YF(7), acc3);
#undef YF

    // ---------- epilogue: rows 0..2 (quad 0) hold the 3 output channels ----------
    if (quad == 0) {
        const int pix = wv * 16 + lane16;
        const int X = X0 + pix;
        const float uy = ((cy + 1.f) * hn - 1.f) * 0.5f;
        const float fy = floorf(uy);
        const float wy = uy - fy;
        const int y0i = min(max((int)fy, 0), hn - 1);
        const int y1i = min(max((int)fy + 1, 0), hn - 1);
        const float cx = -1.f + 1.f / Wn + (2.f / Wn) * (float)X;
        const float ux = ((cx + 1.f) * wn - 1.f) * 0.5f;
        const float fx = floorf(ux);
        const float wx = ux - fx;
        const int x0i = min(max((int)fx, 0), wn - 1);
        const int x1i = min(max((int)fx + 1, 0), wn - 1);
        const float w00b = (1.f - wy) * (1.f - wx), w01b = (1.f - wy) * wx;
        const float w10b = wy * (1.f - wx), w11b = wy * wx;
#pragma unroll
        for (int r = 0; r < 3; r++) {
            const float* scb = sc + (b * 3 + r) * (hn * wn);
            const float samp = scb[y0i * wn + x0i] * w00b + scb[y0i * wn + x1i] * w01b
                             + scb[y1i * wn + x0i] * w10b + scb[y1i * wn + x1i] * w11b;
            out[((b * 3 + r) * Hn + Y) * Wn + X] = acc3[r] + b2v[r] + samp;
        }
    }
}

extern "C" void kernel_launch(void* const* d_in, const int* in_sizes, int n_in,
                              void* d_out, int out_size, void* d_ws, size_t ws_size,
                              hipStream_t stream)
{
    const float* feat = (const float*)d_in[0];
    const float* w00  = (const float*)d_in[1];
    const float* b00  = (const float*)d_in[2];
    const float* w1   = (const float*)d_in[3];
    const float* b1   = (const float*)d_in[4];
    const float* w2   = (const float*)d_in[5];
    const float* b2   = (const float*)d_in[6];
    const float* ws1  = (const float*)d_in[7];
    const float* bs1  = (const float*)d_in[8];
    const float* ws2  = (const float*)d_in[9];
    const float* bs2  = (const float*)d_in[10];
    float* out = (float*)d_out;

    __bf16* wb    = (__bf16*)d_ws;
    float* scbuf  = (float*)((char*)d_ws + SC_OFF_BYTES);
    float* b1eff  = (float*)((char*)d_ws + B1EFF_OFF_BYTES);
    float* featT  = (float*)((char*)d_ws + FEATT_OFF_BYTES);

    prep_all<<<FRAG_BLOCKS + 1 + SC_BLOCKS, 256, 0, stream>>>(
        w00, w1, w2, b00, b1, feat, ws1, bs1, ws2, bs2, wb, b1eff, scbuf, featT);
    liif_main<<<Bn * Hn * (Wn / TM), 256, 0, stream>>>(featT, b1eff, b2, wb, scbuf, out);
}